// Round 5
// baseline (1546.190 us; speedup 1.0000x reference)
//
#include <hip/hip_runtime.h>

namespace {
constexpr int ICH = 8, IH = 128, IW = 128;
constexpr int PH = 31;
constexpr float EPS = 1e-5f;
constexpr float CNT = 126.f * 126.f;       // valid positions per channel
constexpr int TOTAL_OUT = 128 * 64 * PH * PH;

__device__ __forceinline__ void gll16(const void* g, void* l) {
  __builtin_amdgcn_global_load_lds((const __attribute__((address_space(1))) void*)g,
                                   (__attribute__((address_space(3))) void*)l, 16, 0, 0);
}

// Force a wave-uniform value into an SGPR.
__device__ __forceinline__ float sload(const float* p) {
  return __int_as_float(__builtin_amdgcn_readfirstlane(__float_as_int(*p)));
}

// Process staged row RR for all 8 ic. T2 += tap-row2 (completes), T1 += tap1, T0 += tap0.
// Weights wv[] are SGPR-resident; in[] is 4 floats covering out cols 2*lane, 2*lane+1.
#define ROWALL(RR, T2, T1, T0)                                                 \
  {                                                                            \
    _Pragma("unroll") for (int ic = 0; ic < ICH; ++ic) {                       \
      const float* rp = &buf[cur][ic][RR][2 * lane];                           \
      float2 va = *reinterpret_cast<const float2*>(rp);                        \
      float2 vb = (lane < 63) ? *reinterpret_cast<const float2*>(rp + 2)       \
                              : make_float2(0.f, 0.f);                         \
      const float in[4] = {va.x, va.y, vb.x, vb.y};                            \
      _Pragma("unroll") for (int dw = 0; dw < 3; ++dw) {                       \
        T2[0] = fmaf(in[dw], wv[ic * 9 + 6 + dw], T2[0]);                      \
        T2[1] = fmaf(in[dw + 1], wv[ic * 9 + 6 + dw], T2[1]);                  \
        T1[0] = fmaf(in[dw], wv[ic * 9 + 3 + dw], T1[0]);                      \
        T1[1] = fmaf(in[dw + 1], wv[ic * 9 + 3 + dw], T1[1]);                  \
        T0[0] = fmaf(in[dw], wv[ic * 9 + dw], T0[0]);                          \
        T0[1] = fmaf(in[dw + 1], wv[ic * 9 + dw], T0[1]);                      \
      }                                                                        \
    }                                                                          \
  }

#define FIN(T, DOSTATS, RE)                                                    \
  {                                                                            \
    float f0 = T[0], f1 = T[1];                                                \
    if (DOSTATS) {                                                             \
      s1 += m * (f0 + f1);                                                     \
      s2 += m * fmaf(f0, f0, f1 * f1);                                         \
    }                                                                          \
    RE = fmaxf(flip * f0, flip * f1);                                          \
  }

#define ZERO2(T) { T[0] = 0.f; T[1] = 0.f; }

// One 4-row stage: completes output rows 4S-2, 4S-1, 4S, 4S+1 (names X,Y,X... rolling).
#define STAGE(S, X, Y, Z, DOS01, DOWIN)                                        \
  {                                                                            \
    __syncthreads();                                                           \
    const int cur = (S) & 1;                                                   \
    if ((S) < 31) issue(4 * ((S) + 1), cur ^ 1);                               \
    float re0, re1, re2, re3;                                                  \
    ROWALL(0, X, Y, Z) FIN(X, DOS01, re0) ZERO2(X)                             \
    ROWALL(1, Y, Z, X) FIN(Y, DOS01, re1) ZERO2(Y)                             \
    if (DOWIN) {                                                               \
      float wfin = fmaxf(wprev, fmaxf(re0, re1));                              \
      wfin = fmaxf(wfin, __shfl_xor(wfin, 1, 64));                             \
      if ((lane & 1) == 0 && lane < 62)                                        \
        outraw[((S) - 1) * PH + (lane >> 1)] = flip * wfin;                    \
    }                                                                          \
    ROWALL(2, Z, X, Y) FIN(Z, true, re2) ZERO2(Z)                              \
    ROWALL(3, X, Y, Z) FIN(X, true, re3) ZERO2(X)                              \
    wprev = fmaxf(re2, re3);                                                   \
  }

__global__ __launch_bounds__(512, 4) void conv_pool_raw(
    const float* __restrict__ x, const float* __restrict__ cw,
    const float* __restrict__ cb, const float* __restrict__ gnw,
    const float* __restrict__ sc, float* __restrict__ out,
    float* __restrict__ ws) {
  __shared__ float buf[2][ICH][4][IW];   // 32768 B, linear (global_load_lds dest)
  __shared__ float red[8][2];

  const int bid = blockIdx.x;            // 1024 blocks = 128 images x 8 group-pairs
  const int xcd = bid & 7;               // image's 8 blocks share one XCD L2
  const int kb = bid >> 3;               // 0..127
  const int n = xcd * 16 + (kb >> 3);
  const int gp = kb & 7;                 // group-pair (2 groups = 8 channels)
  const int t = threadIdx.x;
  const int wch = t >> 6;                // wave = one output channel (0..7)
  const int lane = t & 63;               // lane = 2 output cols (2*lane, 2*lane+1)
  const int gc = gp * 8 + wch;

  const int gcs = __builtin_amdgcn_readfirstlane(gc);
  float wv[72];                          // wave-uniform -> SGPR file, 0 VGPR cost
#pragma unroll
  for (int k = 0; k < 72; ++k) wv[k] = sload(cw + gcs * 72 + k);

  const float flip = (gnw[gcs] * sc[gcs] >= 0.f) ? 1.f : -1.f;
  const float m = (lane < 63) ? 1.f : 0.f;   // lane 63: cols 126,127 invalid
  const float* xn = x + (size_t)n * ICH * IH * IW;
  float* outraw = out + ((size_t)n * 64 + gc) * (PH * PH);

  // Wave wch stages its own ic=wch rows {k*2, k*2+1}: 2 x 1KB chunks, LDS linear.
  auto issue = [&](int br, int which) {
#pragma unroll
    for (int k = 0; k < 2; ++k) {
      const int r2 = k * 2;
      gll16(xn + (size_t)(wch * IH + br + r2) * IW + lane * 4,
            &buf[which][wch][r2][0]);
    }
  };

  issue(0, 0);

  float s1 = 0.f, s2 = 0.f, wprev = 0.f;
  float A0[2] = {0, 0}, A1[2] = {0, 0}, A2[2] = {0, 0};

  STAGE(0, A0, A1, A2, false, false)
  for (int s = 1; s <= 28; s += 3) {     // name-rotation has period 3
    STAGE(s,     A1, A2, A0, true, true)
    STAGE(s + 1, A2, A0, A1, true, true)
    STAGE(s + 2, A0, A1, A2, true, true)
  }
  STAGE(31, A1, A2, A0, true, true)      // finalizes window 30; rows 124,125 stats

  // ---- per-channel reduction over the wave's 64 lanes ----
#pragma unroll
  for (int off = 32; off > 0; off >>= 1) {
    s1 += __shfl_down(s1, off, 64);
    s2 += __shfl_down(s2, off, 64);
  }
  if (lane == 0) {
    const float bc = cb[gcs];            // fold conv bias analytically
    red[wch][0] = s1 + CNT * bc;
    red[wch][1] = s2 + 2.f * bc * s1 + CNT * bc * bc;
  }
  __syncthreads();
  if (t < 2) {                           // one thread per group in this pair
    float S1 = red[t * 4 + 0][0] + red[t * 4 + 1][0] + red[t * 4 + 2][0] + red[t * 4 + 3][0];
    float S2 = red[t * 4 + 0][1] + red[t * 4 + 1][1] + red[t * 4 + 2][1] + red[t * 4 + 3][1];
    constexpr float invN = 1.f / (4.f * CNT);
    float mean = S1 * invN;
    float var = S2 * invN - mean * mean;
    int G = n * 16 + gp * 2 + t;
    ws[G * 2] = mean;
    ws[G * 2 + 1] = rsqrtf(var + EPS);
  }
}

__global__ __launch_bounds__(256) void gn_affine_clamp(
    float* __restrict__ out, const float* __restrict__ ws,
    const float* __restrict__ gnw, const float* __restrict__ gnb,
    const float* __restrict__ sc, const float* __restrict__ cb) {
  int i = blockIdx.x * 256 + threadIdx.x;
  const int stride = gridDim.x * 256;
  for (; i < TOTAL_OUT; i += stride) {
    int c = (i / 961) & 63;              // 961 = 31*31
    int n = i / 61504;                   // 61504 = 64*961
    int G = n * 16 + (c >> 2);
    float mean = ws[G * 2], inv = ws[G * 2 + 1];
    float gw = gnw[c];
    float A = gw * inv * sc[c];
    float B = (gnb[c] - mean * inv * gw) * sc[c] + A * cb[c];
    float v = fmaf(A, out[i], B);        // out[i] holds the selected raw extreme
    out[i] = fminf(fmaxf(v, 0.f), 1.f);
  }
}
}  // namespace

extern "C" void kernel_launch(void* const* d_in, const int* in_sizes, int n_in,
                              void* d_out, int out_size, void* d_ws, size_t ws_size,
                              hipStream_t stream) {
  const float* x   = (const float*)d_in[0];
  const float* cw  = (const float*)d_in[1];
  const float* cb  = (const float*)d_in[2];
  const float* gnw = (const float*)d_in[3];
  const float* gnb = (const float*)d_in[4];
  const float* sc  = (const float*)d_in[5];
  float* out = (float*)d_out;
  float* ws  = (float*)d_ws;             // 2048 groups x {mean, inv} = 16 KB
  hipLaunchKernelGGL(conv_pool_raw, dim3(1024), dim3(512), 0, stream,
                     x, cw, cb, gnw, sc, out, ws);
  hipLaunchKernelGGL(gn_affine_clamp, dim3(2048), dim3(256), 0, stream,
                     out, ws, gnw, gnb, sc, cb);
}

// Round 6
// 292.023 us; speedup vs baseline: 5.2948x; 5.2948x over previous
//
#include <hip/hip_runtime.h>
#include <hip/hip_fp16.h>

namespace {
constexpr int ICH = 8, IH = 128, IW = 128;
constexpr int CPG = 4, PH = 31;
constexpr float EPS = 1e-5f;
constexpr float MPX = 126.f * 126.f;

__device__ __forceinline__ void gll16(const void* g, void* l) {
  __builtin_amdgcn_global_load_lds((const __attribute__((address_space(1))) void*)g,
                                   (__attribute__((address_space(3))) void*)l, 16, 0, 0);
}

// Process staged row RR: T2 += tap-row2 (completes), T1 += tap-row1, T0 += tap-row0.
#define ROW(RR, T2, T1, T0)                                                    \
  {                                                                            \
    _Pragma("unroll") for (int i4 = 0; i4 < 4; ++i4) {                         \
      const float* rp = bp + ((4 * p + i4) * 4 + (RR)) * IW + 4 * j;           \
      float4 v4 = *reinterpret_cast<const float4*>(rp);                        \
      float2 v2 = (j < 31) ? *reinterpret_cast<const float2*>(rp + 4)          \
                           : make_float2(0.f, 0.f);                            \
      float in[6] = {v4.x, v4.y, v4.z, v4.w, v2.x, v2.y};                      \
      _Pragma("unroll") for (int dw = 0; dw < 3; ++dw) {                       \
        const float w0 = wf[i4 * 9 + dw];                                      \
        const float w1 = wf[i4 * 9 + 3 + dw];                                  \
        const float w2 = wf[i4 * 9 + 6 + dw];                                  \
        _Pragma("unroll") for (int q = 0; q < 4; ++q) {                        \
          T2[q] = fmaf(in[q + dw], w2, T2[q]);                                 \
          T1[q] = fmaf(in[q + dw], w1, T1[q]);                                 \
          T0[q] = fmaf(in[q + dw], w0, T0[q]);                                 \
        }                                                                      \
      }                                                                        \
    }                                                                          \
  }

// Combine ic-halves, accumulate stats (masked col tail), emit flipped extreme.
#define FIN(T, DOSTATS, RE)                                                    \
  {                                                                            \
    float f0 = T[0] + __shfl_xor(T[0], 32, 64);                                \
    float f1 = T[1] + __shfl_xor(T[1], 32, 64);                                \
    float f2 = T[2] + __shfl_xor(T[2], 32, 64);                                \
    float f3 = T[3] + __shfl_xor(T[3], 32, 64);                                \
    if (DOSTATS) {                                                             \
      s1 += f0 + f1 + m23 * (f2 + f3);                                         \
      float qa = fmaf(f0, f0, f1 * f1);                                        \
      float qb = fmaf(f2, f2, f3 * f3);                                        \
      s2 += qa + m23 * qb;                                                     \
    }                                                                          \
    RE = fmaxf(fmaxf(flip * f0, flip * f1), fmaxf(flip * f2, flip * f3));      \
  }

#define ZERO(T) { T[0] = 0.f; T[1] = 0.f; T[2] = 0.f; T[3] = 0.f; }

// One 4-row stage. Completes output rows 4S-2, 4S-1, 4S, 4S+1 (names X,Y,Z,X).
#define STAGE(S, X, Y, Z, DOS01, DOWIN)                                        \
  {                                                                            \
    __syncthreads();                                                           \
    const int cur = (S) & 1;                                                   \
    if ((S) < 31) issue(4 * ((S) + 1), cur ^ 1);                               \
    const float* bp = &buf[cur][0][0][0];                                      \
    float re0, re1, re2, re3;                                                  \
    ROW(0, X, Y, Z) FIN(X, DOS01, re0) ZERO(X)                                 \
    ROW(1, Y, Z, X) FIN(Y, DOS01, re1) ZERO(Y)                                 \
    if (DOWIN) {                                                               \
      float wfin = fmaxf(wprev, fmaxf(re0, re1));                              \
      if (p == 0 && j < 31) mm[c][(S) - 1][j] = __float2half(flip * wfin);     \
    }                                                                          \
    ROW(2, Z, X, Y) FIN(Z, true, re2) ZERO(Z)                                  \
    ROW(3, X, Y, Z) FIN(X, true, re3) ZERO(X)                                  \
    wprev = fmaxf(re2, re3);                                                   \
  }

// min-waves 2 -> VGPR budget 256: allocator fits ~90-reg demand, NO spills.
// (min 4 pinned budget to 64 and spilled ~2.5 GB to scratch in R2-R5.)
__global__ __launch_bounds__(256, 2) void fused_conv_gn_pool(
    const float* __restrict__ x, const float* __restrict__ cw,
    const float* __restrict__ cb, const float* __restrict__ gnw,
    const float* __restrict__ gnb, const float* __restrict__ sc,
    float* __restrict__ out) {
  __shared__ float buf[2][ICH][4][IW];   // 32768 B, linear (global_load_lds dest)
  __shared__ __half mm[CPG][PH][PH];     // 7688 B
  __shared__ float red[8];
  __shared__ float stats[2];

  const int bid = blockIdx.x;
  const int xcd = bid & 7;               // image's 16 groups share one XCD L2
  const int kb = bid >> 3;
  const int n = xcd * 16 + (kb >> 4);
  const int g = kb & 15;
  const int t = threadIdx.x;
  const int c = t >> 6;                  // wave = output channel within group
  const int u = t & 63;
  const int p = u >> 5;                  // ic-half: 0 -> ic 0..3, 1 -> ic 4..7
  const int j = u & 31;                  // output cols 4j..4j+3
  const int gc = g * CPG + c;

  float wf[36];                          // this lane's 4 ics x 9 taps
  {
    const float4* wp = reinterpret_cast<const float4*>(cw + gc * 72 + p * 36);
#pragma unroll
    for (int q = 0; q < 9; ++q) {
      float4 v = wp[q];
      wf[4 * q + 0] = v.x; wf[4 * q + 1] = v.y;
      wf[4 * q + 2] = v.z; wf[4 * q + 3] = v.w;
    }
  }
  const float flip = ((gnw[gc] * sc[gc]) >= 0.f) ? 1.f : -1.f;
  const float m23 = (j < 31) ? 1.f : 0.f;   // lane 31: only cols 124,125 valid

  const float* xn = x + (size_t)n * ICH * IH * IW;

  // Stage 4 input rows (all 8 ic) into buf[which]; 16 x 1KB wave-chunks, 4/wave.
  auto issue = [&](int br, int which) {
#pragma unroll
    for (int k = 0; k < 4; ++k) {
      const int m = c * 4 + k;
      const int ic = m >> 1;
      const int r2 = (m & 1) * 2;        // rows r2, r2+1 of the stage
      const float* gp = xn + (size_t)(ic * IH + br + r2) * IW + u * 4;
      gll16(gp, &buf[which][ic][r2][0]);
    }
  };

  issue(0, 0);

  float s1 = 0.f, s2 = 0.f, wprev = 0.f;
  float A0[4] = {0, 0, 0, 0}, A1[4] = {0, 0, 0, 0}, A2[4] = {0, 0, 0, 0};

  // Stage 0: completed rows -2,-1 are invalid (no stats, no window).
  STAGE(0, A0, A1, A2, false, false)
  // Stages 1..30 in 3-phase triplets (pending-name permutation has period 3).
  for (int s = 1; s <= 28; s += 3) {
    STAGE(s,     A1, A2, A0, true, true)
    STAGE(s + 1, A2, A0, A1, true, true)
    STAGE(s + 2, A0, A1, A2, true, true)
  }
  // Stage 31 (31 % 3 == 1 -> phase (A1,A2,A0)); finalizes window 30.
  STAGE(31, A1, A2, A0, true, true)

  // ---- block reduction (each value counted twice across ic-halves -> 0.5x) ----
#pragma unroll
  for (int off = 32; off > 0; off >>= 1) {
    s1 += __shfl_down(s1, off, 64);
    s2 += __shfl_down(s2, off, 64);
  }
  const float bc = cb[gc];
  if (u == 0) {
    float t1 = 0.5f * s1, t2 = 0.5f * s2;       // true raw per-channel sums
    red[c * 2] = t1 + MPX * bc;                 // add bias analytically
    red[c * 2 + 1] = t2 + 2.f * bc * t1 + MPX * bc * bc;
  }
  __syncthreads();
  if (t == 0) {
    float S1 = red[0] + red[2] + red[4] + red[6];
    float S2 = red[1] + red[3] + red[5] + red[7];
    constexpr float invN = 1.f / (CPG * 126.f * 126.f);
    float mean = S1 * invN;
    float var = S2 * invN - mean * mean;
    stats[0] = mean;
    stats[1] = rsqrtf(var + EPS);
  }
  __syncthreads();
  const float mean = stats[0], inv = stats[1];

  // ---- epilogue: affine(+bias fold) + clamp + store ----
  float* outp = out + ((size_t)n * 64 + g * CPG) * (PH * PH);
  for (int kk = 0; kk < 16; ++kk) {
    int idx = t + kk * 256;
    if (idx < CPG * PH * PH) {
      int cc = idx / (PH * PH);
      int rem = idx - cc * (PH * PH);
      float e = __half2float(mm[cc][rem / PH][rem % PH]);
      int gcc = g * CPG + cc;
      float gw = gnw[gcc];
      float A = gw * inv * sc[gcc];
      float B = (gnb[gcc] - mean * inv * gw) * sc[gcc] + A * cb[gcc];
      float v = fmaf(A, e, B);
      v = fminf(fmaxf(v, 0.f), 1.f);
      outp[cc * (PH * PH) + rem] = v;
    }
  }
}
}  // namespace

extern "C" void kernel_launch(void* const* d_in, const int* in_sizes, int n_in,
                              void* d_out, int out_size, void* d_ws, size_t ws_size,
                              hipStream_t stream) {
  const float* x   = (const float*)d_in[0];
  const float* cw  = (const float*)d_in[1];
  const float* cb  = (const float*)d_in[2];
  const float* gnw = (const float*)d_in[3];
  const float* gnb = (const float*)d_in[4];
  const float* sc  = (const float*)d_in[5];
  float* out = (float*)d_out;
  hipLaunchKernelGGL(fused_conv_gn_pool, dim3(2048), dim3(256), 0, stream,
                     x, cw, cb, gnw, gnb, sc, out);
}

// Round 7
// 288.560 us; speedup vs baseline: 5.3583x; 1.0120x over previous
//
#include <hip/hip_runtime.h>
#include <hip/hip_fp16.h>

namespace {
constexpr int ICH = 8, IH = 128, IW = 128;
constexpr int CPG = 4, PH = 31;
constexpr int ICS = 516;                 // per-ic LDS block: 4*128 + 4 pad (16B-align)
constexpr float EPS = 1e-5f;
constexpr float MPX = 126.f * 126.f;

typedef float f32x2 __attribute__((ext_vector_type(2)));

__device__ __forceinline__ void gll16(const void* g, void* l) {
  __builtin_amdgcn_global_load_lds((const __attribute__((address_space(1))) void*)g,
                                   (__attribute__((address_space(3))) void*)l, 16, 0, 0);
}

#define FMA2(A, B, C) __builtin_elementwise_fma((A), (B), (C))

// Process staged row RR: T2 += tap-row2 (completes), T1 += tap-row1, T0 += tap-row0.
// Accumulators are f32x2[2] = output cols {4j,4j+1} and {4j+2,4j+3}.
#define ROW(RR, T2, T1, T0)                                                    \
  {                                                                            \
    _Pragma("unroll") for (int i4 = 0; i4 < 4; ++i4) {                         \
      const float* rp = bp + (4 * p + i4) * ICS + (RR) * IW + 4 * j;           \
      float4 v4 = *reinterpret_cast<const float4*>(rp);                        \
      float2 vt = *reinterpret_cast<const float2*>(rp + 4);                    \
      f32x2 pp[5];                                                             \
      pp[0] = (f32x2){v4.x, v4.y}; pp[1] = (f32x2){v4.y, v4.z};                \
      pp[2] = (f32x2){v4.z, v4.w}; pp[3] = (f32x2){v4.w, vt.x};                \
      pp[4] = (f32x2){vt.x, vt.y};                                             \
      _Pragma("unroll") for (int dw = 0; dw < 3; ++dw) {                       \
        const f32x2 w0 = wf2[i4 * 9 + dw];                                     \
        const f32x2 w1 = wf2[i4 * 9 + 3 + dw];                                 \
        const f32x2 w2 = wf2[i4 * 9 + 6 + dw];                                 \
        T2[0] = FMA2(pp[dw], w2, T2[0]);                                       \
        T2[1] = FMA2(pp[dw + 2], w2, T2[1]);                                   \
        T1[0] = FMA2(pp[dw], w1, T1[0]);                                       \
        T1[1] = FMA2(pp[dw + 2], w1, T1[1]);                                   \
        T0[0] = FMA2(pp[dw], w0, T0[0]);                                       \
        T0[1] = FMA2(pp[dw + 2], w0, T0[1]);                                   \
      }                                                                        \
    }                                                                          \
  }

// Combine ic-halves, accumulate stats (masked col tail) into set SI, emit extreme.
#define FIN(T, DOSTATS, SI, RE)                                                \
  {                                                                            \
    float f0 = T[0].x + __shfl_xor(T[0].x, 32, 64);                            \
    float f1 = T[0].y + __shfl_xor(T[0].y, 32, 64);                            \
    float f2 = T[1].x + __shfl_xor(T[1].x, 32, 64);                            \
    float f3 = T[1].y + __shfl_xor(T[1].y, 32, 64);                            \
    if (DOSTATS) {                                                             \
      float g2 = m23 * f2, g3 = m23 * f3;                                      \
      s1v[SI] += (f32x2){f0 + f1, g2 + g3};                                    \
      f32x2 ha = (f32x2){f0, g2}, hb = (f32x2){f1, g3};                        \
      s2v[SI] = FMA2(ha, ha, FMA2(hb, hb, s2v[SI]));                           \
    }                                                                          \
    RE = fmaxf(fmaxf(flip * f0, flip * f1), fmaxf(flip * f2, flip * f3));      \
  }

#define ZERO(T) { T[0] = (f32x2){0.f, 0.f}; T[1] = (f32x2){0.f, 0.f}; }

// One 4-row stage. Completes output rows 4S-2, 4S-1, 4S, 4S+1 (names X,Y,Z,X).
#define STAGE(S, X, Y, Z, DOS01, DOWIN)                                        \
  {                                                                            \
    __syncthreads();                                                           \
    const int cur = (S) & 1;                                                   \
    if ((S) < 31) issue(4 * ((S) + 1), cur ^ 1);                               \
    const float* bp = &buf[cur][0][0];                                         \
    float re0, re1, re2, re3;                                                  \
    ROW(0, X, Y, Z) FIN(X, DOS01, 0, re0) ZERO(X)                              \
    ROW(1, Y, Z, X) FIN(Y, DOS01, 1, re1) ZERO(Y)                              \
    if (DOWIN) {                                                               \
      float wfin = fmaxf(wprev, fmaxf(re0, re1));                              \
      if (p == 0 && j < 31) mm[c][(S) - 1][j] = __float2half(flip * wfin);     \
    }                                                                          \
    ROW(2, Z, X, Y) FIN(Z, true, 0, re2) ZERO(Z)                               \
    ROW(3, X, Y, Z) FIN(X, true, 1, re3) ZERO(X)                               \
    wprev = fmaxf(re2, re3);                                                   \
  }

// min-waves 2 -> VGPR budget 256: fits ~130-reg demand with NO spills.
// (min >= 4 pinned the budget to 64 and spilled GBs to scratch in R2-R5.)
__global__ __launch_bounds__(256, 2) void fused_conv_gn_pool(
    const float* __restrict__ x, const float* __restrict__ cw,
    const float* __restrict__ cb, const float* __restrict__ gnw,
    const float* __restrict__ gnb, const float* __restrict__ sc,
    float* __restrict__ out) {
  __shared__ float buf[2][ICH][ICS];     // 33024 B, linear (global_load_lds dest)
  __shared__ __half mm[CPG][PH][PH];     // 7688 B
  __shared__ float red[8];
  __shared__ float stats[2];

  const int bid = blockIdx.x;
  const int xcd = bid & 7;               // image's 16 groups share one XCD L2
  const int kb = bid >> 3;
  const int n = xcd * 16 + (kb >> 4);
  const int g = kb & 15;
  const int t = threadIdx.x;
  const int c = t >> 6;                  // wave = output channel within group
  const int u = t & 63;
  const int p = u >> 5;                  // ic-half: 0 -> ic 0..3, 1 -> ic 4..7
  const int j = u & 31;                  // output cols 4j..4j+3
  const int gc = g * CPG + c;

  f32x2 wf2[36];                         // this lane's 4 ics x 9 taps, pre-splat
  {
    const float4* wp = reinterpret_cast<const float4*>(cw + gc * 72 + p * 36);
#pragma unroll
    for (int q = 0; q < 9; ++q) {
      float4 v = wp[q];
      wf2[4 * q + 0] = (f32x2){v.x, v.x};
      wf2[4 * q + 1] = (f32x2){v.y, v.y};
      wf2[4 * q + 2] = (f32x2){v.z, v.z};
      wf2[4 * q + 3] = (f32x2){v.w, v.w};
    }
  }
  const float flip = ((gnw[gc] * sc[gc]) >= 0.f) ? 1.f : -1.f;
  const float m23 = (j < 31) ? 1.f : 0.f;   // lane 31: only cols 124,125 valid

  const float* xn = x + (size_t)n * ICH * IH * IW;

  // Stage 4 input rows (all 8 ic) into buf[which]; 16 x 1KB wave-chunks, 4/wave.
  auto issue = [&](int br, int which) {
#pragma unroll
    for (int k = 0; k < 4; ++k) {
      const int m = c * 4 + k;
      const int ic = m >> 1;
      const int r2 = (m & 1) * 2;        // rows r2, r2+1 of the stage
      const float* gp = xn + (size_t)(ic * IH + br + r2) * IW + u * 4;
      gll16(gp, &buf[which][ic][r2 * IW]);
    }
  };

  issue(0, 0);

  float wprev = 0.f;
  f32x2 s1v[2] = {(f32x2){0.f, 0.f}, (f32x2){0.f, 0.f}};
  f32x2 s2v[2] = {(f32x2){0.f, 0.f}, (f32x2){0.f, 0.f}};
  f32x2 A0[2], A1[2], A2[2];
  ZERO(A0) ZERO(A1) ZERO(A2)

  // Stage 0: completed rows -2,-1 are invalid (no stats, no window).
  STAGE(0, A0, A1, A2, false, false)
  // Stages 1..30 in 3-phase triplets (pending-name permutation has period 3).
  for (int s = 1; s <= 28; s += 3) {
    STAGE(s,     A1, A2, A0, true, true)
    STAGE(s + 1, A2, A0, A1, true, true)
    STAGE(s + 2, A0, A1, A2, true, true)
  }
  // Stage 31 (31 % 3 == 1 -> phase (A1,A2,A0)); finalizes window 30.
  STAGE(31, A1, A2, A0, true, true)

  // ---- block reduction (each value counted twice across ic-halves -> 0.5x) ----
  float s1 = s1v[0].x + s1v[0].y + s1v[1].x + s1v[1].y;
  float s2 = s2v[0].x + s2v[0].y + s2v[1].x + s2v[1].y;
#pragma unroll
  for (int off = 32; off > 0; off >>= 1) {
    s1 += __shfl_down(s1, off, 64);
    s2 += __shfl_down(s2, off, 64);
  }
  const float bc = cb[gc];
  if (u == 0) {
    float t1 = 0.5f * s1, t2 = 0.5f * s2;       // true raw per-channel sums
    red[c * 2] = t1 + MPX * bc;                 // add bias analytically
    red[c * 2 + 1] = t2 + 2.f * bc * t1 + MPX * bc * bc;
  }
  __syncthreads();
  if (t == 0) {
    float S1 = red[0] + red[2] + red[4] + red[6];
    float S2 = red[1] + red[3] + red[5] + red[7];
    constexpr float invN = 1.f / (CPG * 126.f * 126.f);
    float mean = S1 * invN;
    float var = S2 * invN - mean * mean;
    stats[0] = mean;
    stats[1] = rsqrtf(var + EPS);
  }
  __syncthreads();
  const float mean = stats[0], inv = stats[1];

  // ---- epilogue: affine(+bias fold) + clamp + store ----
  float* outp = out + ((size_t)n * 64 + g * CPG) * (PH * PH);
  for (int kk = 0; kk < 16; ++kk) {
    int idx = t + kk * 256;
    if (idx < CPG * PH * PH) {
      int cc = idx / (PH * PH);
      int rem = idx - cc * (PH * PH);
      float e = __half2float(mm[cc][rem / PH][rem % PH]);
      int gcc = g * CPG + cc;
      float gw = gnw[gcc];
      float A = gw * inv * sc[gcc];
      float B = (gnb[gcc] - mean * inv * gw) * sc[gcc] + A * cb[gcc];
      float v = fmaf(A, e, B);
      v = fminf(fmaxf(v, 0.f), 1.f);
      outp[cc * (PH * PH) + rem] = v;
    }
  }
}
}  // namespace

extern "C" void kernel_launch(void* const* d_in, const int* in_sizes, int n_in,
                              void* d_out, int out_size, void* d_ws, size_t ws_size,
                              hipStream_t stream) {
  const float* x   = (const float*)d_in[0];
  const float* cw  = (const float*)d_in[1];
  const float* cb  = (const float*)d_in[2];
  const float* gnw = (const float*)d_in[3];
  const float* gnb = (const float*)d_in[4];
  const float* sc  = (const float*)d_in[5];
  float* out = (float*)d_out;
  hipLaunchKernelGGL(fused_conv_gn_pool, dim3(2048), dim3(256), 0, stream,
                     x, cw, cb, gnw, gnb, sc, out);
}